// Round 8
// baseline (225.336 us; speedup 1.0000x reference)
//
#include <hip/hip_runtime.h>

// Segment-mean over SORTED batch_ids — single kernel + tiny flag memset.
// 4-way row-split with in-kernel "last-arrival" combine.
//
// Grid = G*4 blocks x 256 thr (8 blocks/CU = 32 waves/CU, full occupancy).
// Block (g,q) sums quarter-q of graph g's contiguous row range with full-row
// nontemporal float4 loads (64 lanes x 16B = 1KB/wave-instr), writes a 1KB
// partial to ws, then bumps flags[g] (device-scope ACQ_REL). flags are
// ZEROED every call by a hipMemsetAsync node (R7 bug: poisoned flags made
// the 2nd arrival the finisher). The 4th arrival (old==3) sums the 4
// partials in FIXED index order (deterministic) and writes the mean.
// Per-CU work = 8 quarter-chunks from 8 distinct graphs -> finish-time tail
// ~+9.6% -> ~+4.8% of the 32.6us stream time.

typedef float f32x4 __attribute__((ext_vector_type(4)));

#define SPLIT 4

__device__ __forceinline__ int lower_bound64(const int* __restrict__ ids,
                                             int N, int v, int lane)
{
    // Wave-parallel 64-ary lower_bound: 64 probes/round, ballot+popcount
    // narrows 64x. ~3 gather rounds for N=200000 vs 18 serial rounds.
    int lo = 0, hi = N;
    while (hi - lo > 64) {
        const int step = (hi - lo + 63) >> 6;
        int p = lo + lane * step;
        p = p < hi - 1 ? p : hi - 1;
        const int cnt = (int)__popcll(__ballot(ids[p] < v));  // prefix length
        int nlo = lo, nhi = hi;
        if (cnt > 0) { int q = lo + (cnt - 1) * step; q = q < hi - 1 ? q : hi - 1; nlo = q + 1; }
        if (cnt < 64) { int q = lo + cnt * step;       q = q < hi - 1 ? q : hi - 1; nhi = q; }
        lo = nlo; hi = nhi;
    }
    const int p  = lo + lane;
    const bool lt = (p < hi) ? (ids[p] < v) : false;
    return lo + (int)__popcll(__ballot(lt));
}

__global__ __launch_bounds__(256) void segmean_kernel(
    const float* __restrict__ x,
    const int*   __restrict__ ids,
    float*       __restrict__ out,
    float*       __restrict__ part,    // ws: [G*SPLIT][D] partial sums
    unsigned int* __restrict__ flags,  // ws: [G] arrival counters (zeroed per call)
    int N, int D, int G)
{
    const int bid = (int)blockIdx.x;
    const int g   = bid >> 2;          // SPLIT == 4
    const int q   = bid & 3;
    const int t   = (int)threadIdx.x;
    const int wv  = t >> 6;
    const int ln  = t & 63;

    __shared__ int sb[2];
    if (wv == 0)      { const int s = lower_bound64(ids, N, g,     ln); if (ln == 0) sb[0] = s; }
    else if (wv == 1) { const int e = lower_bound64(ids, N, g + 1, ln); if (ln == 0) sb[1] = e; }
    __syncthreads();
    const int start = sb[0];
    const int end   = sb[1];
    const int count = end - start;

    // This block's quarter of the row range (contiguous full rows).
    const int chunk = (count + SPLIT - 1) >> 2;
    const int r0 = start + q * chunk;
    const int r1 = (r0 + chunk < end) ? (r0 + chunk) : end;

    const int rowoff = wv;             // 4 rows per block-iteration
    const int col    = ln << 2;        // 64 lanes x float4 = full 1KB row

    f32x4 acc = (f32x4)(0.f);
    #pragma unroll 4
    for (int r = r0 + rowoff; r < r1; r += 4) {
        acc += __builtin_nontemporal_load(
            reinterpret_cast<const f32x4*>(x + (size_t)r * (size_t)D + col));
    }

    // Block-reduce 4 rowoff groups -> 64 lanes hold the chunk's column sums.
    __shared__ f32x4 sd[256];
    sd[t] = acc;
    __syncthreads();
    if (t < 128) sd[t] += sd[t + 128];
    __syncthreads();
    if (t < 64) {
        const f32x4 s = sd[t] + sd[t + 64];
        *reinterpret_cast<f32x4*>(part + (size_t)bid * (size_t)D + col) = s;
    }
    __syncthreads();   // all partial stores drained (vmcnt0) before the flag bump

    __shared__ int sfin;
    if (t == 0) {
        __threadfence();   // publish block's stores device-wide (cache-granular)
        const unsigned int old = __hip_atomic_fetch_add(
            &flags[g], 1u, __ATOMIC_ACQ_REL, __HIP_MEMORY_SCOPE_AGENT);
        sfin = (old == 3u) ? 1 : 0;    // true 4th arrival (flags zeroed per call)
    }
    __syncthreads();

    if (sfin && t < 64) {
        const float* p = part + (size_t)(g << 2) * (size_t)D;
        const f32x4 a = *reinterpret_cast<const f32x4*>(p + col);
        const f32x4 b = *reinterpret_cast<const f32x4*>(p + (size_t)D + col);
        const f32x4 c = *reinterpret_cast<const f32x4*>(p + 2 * (size_t)D + col);
        const f32x4 d = *reinterpret_cast<const f32x4*>(p + 3 * (size_t)D + col);
        const float inv = 1.0f / (float)count;   // empty segment: NaN, matches ref 0/0
        const f32x4 o = ((a + b) + (c + d)) * inv;
        *reinterpret_cast<f32x4*>(out + (size_t)g * (size_t)D + col) = o;
    }
}

extern "C" void kernel_launch(void* const* d_in, const int* in_sizes, int n_in,
                              void* d_out, int out_size, void* d_ws, size_t ws_size,
                              hipStream_t stream) {
    const float* x   = (const float*)d_in[0];
    const int*   ids = (const int*)d_in[1];
    float*       out = (float*)d_out;

    const int N = in_sizes[1];            // 200000 rows
    const int D = in_sizes[0] / N;        // 256 features
    const int G = out_size / D;           // 512 graphs

    float*        part  = (float*)d_ws;                       // G*SPLIT*D floats = 2 MB
    unsigned int* flags = (unsigned int*)((char*)d_ws + (size_t)G * SPLIT * D * sizeof(float));

    hipMemsetAsync(flags, 0, (size_t)G * sizeof(unsigned int), stream);
    segmean_kernel<<<dim3(G * SPLIT), dim3(256), 0, stream>>>(
        x, ids, out, part, flags, N, D, G);
}

// Round 9
// 37.222 us; speedup vs baseline: 6.0538x; 6.0538x over previous
//
#include <hip/hip_runtime.h>

// Segment-mean over SORTED batch_ids. One 1024-thread block per graph
// (512 blocks = 2 blocks/CU = 32 waves/CU, full occupancy). Full-row
// contiguous nontemporal float4 reads (64 lanes x 16B = 1KB per wave
// instruction; x is a read-once 205MB stream).
//
// Segment boundaries via wave-parallel 64-ary lower_bound (ballot+popcount
// narrows 64x per gather round; ~3 rounds for N=200000). Wave 0 finds start,
// wave 1 finds end, broadcast via LDS.
//
// NOTE (R2/R3/R8 post-mortems): the ~+9.6% CU finish-time tail from Binomial
// segment-size variance is NOT worth chasing — column-split (R2) kills DRAM
// burst length, a combine kernel (R3) costs +2us in dispatch overhead, and a
// per-block agent-scope fence+atomic combine (R8) collapses streaming to
// 480 GB/s (225us) via per-XCD L2 writeback/invalidate storms.

typedef float f32x4 __attribute__((ext_vector_type(4)));

__device__ __forceinline__ int lower_bound64(const int* __restrict__ ids,
                                             int N, int v, int lane)
{
    int lo = 0, hi = N;
    while (hi - lo > 64) {
        const int step = (hi - lo + 63) >> 6;
        int p = lo + lane * step;
        p = p < hi - 1 ? p : hi - 1;
        const int cnt = (int)__popcll(__ballot(ids[p] < v));  // prefix length
        int nlo = lo, nhi = hi;
        if (cnt > 0) { int q = lo + (cnt - 1) * step; q = q < hi - 1 ? q : hi - 1; nlo = q + 1; }
        if (cnt < 64) { int q = lo + cnt * step;       q = q < hi - 1 ? q : hi - 1; nhi = q; }
        lo = nlo; hi = nhi;
    }
    const int p  = lo + lane;
    const bool lt = (p < hi) ? (ids[p] < v) : false;
    return lo + (int)__popcll(__ballot(lt));
}

__global__ __launch_bounds__(1024) void segmean_kernel(
    const float* __restrict__ x,
    const int*   __restrict__ ids,
    float*       __restrict__ out,
    int N, int D, int G)
{
    const int g  = (int)blockIdx.x;
    const int t  = (int)threadIdx.x;
    const int wv = t >> 6;
    const int ln = t & 63;

    __shared__ int sb[2];
    if (wv == 0)      { const int s = lower_bound64(ids, N, g,     ln); if (ln == 0) sb[0] = s; }
    else if (wv == 1) { const int e = lower_bound64(ids, N, g + 1, ln); if (ln == 0) sb[1] = e; }
    __syncthreads();
    const int start = sb[0];
    const int end   = sb[1];
    const int count = end - start;

    const int rowoff = wv;              // 16 rows per block-iteration
    const int col    = ln << 2;         // 64 lanes x float4 = full 1KB row

    f32x4 acc = (f32x4)(0.f);
    #pragma unroll 8
    for (int r = start + rowoff; r < end; r += 16) {
        acc += __builtin_nontemporal_load(
            reinterpret_cast<const f32x4*>(x + (size_t)r * (size_t)D + col));
    }

    // Tree-reduce the 16 rowoff groups (index+k*64 keeps the same column).
    __shared__ f32x4 sd[1024];   // 16 KiB
    sd[t] = acc;
    __syncthreads();
    if (t < 512) sd[t] += sd[t + 512];
    __syncthreads();
    if (t < 256) sd[t] += sd[t + 256];
    __syncthreads();
    if (t < 128) sd[t] += sd[t + 128];
    __syncthreads();
    if (t < 64) {
        const f32x4 s = sd[t] + sd[t + 64];
        const float inv = 1.0f / (float)count;  // empty segment: NaN, matches ref 0/0
        const f32x4 o = s * inv;
        *reinterpret_cast<f32x4*>(out + (size_t)g * (size_t)D + col) = o;
    }
}

extern "C" void kernel_launch(void* const* d_in, const int* in_sizes, int n_in,
                              void* d_out, int out_size, void* d_ws, size_t ws_size,
                              hipStream_t stream) {
    const float* x   = (const float*)d_in[0];
    const int*   ids = (const int*)d_in[1];
    float*       out = (float*)d_out;

    const int N = in_sizes[1];            // 200000 rows
    const int D = in_sizes[0] / N;        // 256 features
    const int G = out_size / D;           // 512 graphs

    segmean_kernel<<<dim3(G), dim3(1024), 0, stream>>>(x, ids, out, N, D, G);
}